// Round 21
// baseline (294.021 us; speedup 1.0000x reference)
//
#include <hip/hip_runtime.h>
#include <cstdint>

#define HH 76
#define WW 128
#define AA 9
#define HWH (HH * WW)          // 9728
#define KK (HWH * AA)          // 87552
#define NSEL 6000
#define NCH 94                 // ceil(6000/64)
#define NPAD (NCH * 64)        // 6016
#define NOUT 1000
#define NMS_T 0.7
#define NTRI (NCH * (NCH + 1) / 2)  // 4465 upper-tri tiles
#define MASK_BLOCKS 1117            // ceil(NTRI/4), 4 waves/block
#define SELCAP 16384
#define NBIN 16384                  // key>>16 - 0x8000 bin space (scores in [0,2))

// light barrier: order LDS, but DO NOT drain vmcnt (global prefetch stays in flight)
#define LBAR() asm volatile("s_waitcnt lgkmcnt(0)\n\ts_barrier" ::: "memory")

// ---- workspace layout (bytes) ---- (NO zeroing: all control state written
// in-kernel before use each launch)
#define WS_HIST 0              // u32[16384] per-bin counts, ACTIVE BINS ONLY
#define WS_BINB 65536          // u32 threshold bin
#define WS_NACT 65540          // u32 active-bin count
#define WS_ACTIVE 65552        // u32[8192] active bin list
#define WS_BINSTART 98320      // u32[16384] rank base per bin (active only)
#define WS_SELKEYS 163856      // u64[16384]
#define WS_BOXES 294928        // float4[6016] (16-aligned)
#define WS_MASK 391184         // u64 supT[NCH][NPAD]: supT[c][j] bit k = (c*64+k) suppresses j

// base anchors from generate_anchors() (numpy fp64, exact small values)
__device__ __constant__ float c_ax1[9] = {-84.f, -176.f, -360.f, -56.f, -120.f, -248.f, -36.f, -80.f, -168.f};
__device__ __constant__ float c_ay1[9] = {-40.f, -88.f, -184.f, -56.f, -120.f, -248.f, -80.f, -168.f, -344.f};
__device__ __constant__ float c_ax2[9] = {99.f, 191.f, 375.f, 71.f, 135.f, 263.f, 51.f, 95.f, 183.f};
__device__ __constant__ float c_ay2[9] = {55.f, 103.f, 199.f, 71.f, 135.f, 263.f, 95.f, 183.f, 359.f};

__device__ __forceinline__ unsigned score_key(float s) {
    unsigned u = __float_as_uint(s);
    return (u & 0x80000000u) ? ~u : (u | 0x80000000u);
}

// monotone bucketing into 16K bins (exact for scores in [0,2); clamped ends stay order-valid)
__device__ __forceinline__ int key_bin(unsigned key) {
    int bi = (int)(key >> 16) - 0x8000;
    return bi < 0 ? 0 : (bi > NBIN - 1 ? NBIN - 1 : bi);
}

// intra-chunk greedy via Jacobi fixpoint: converges in chain-depth+1 passes
// (typ. 3-5), one ballot per pass. Unique fixpoint == greedy order.
__device__ __forceinline__ unsigned long long chunk_scan_fix(unsigned long long col,
                                                             unsigned long long alive_in) {
    unsigned long long kept = alive_in;
    while (true) {
        unsigned long long sup = __ballot((int)((col & kept) != 0ull));
        unsigned long long kept2 = alive_in & ~sup;
        if (kept2 == kept) return kept;
        kept = kept2;
    }
}

// fp64 decode+clip of anchor-order index i -> boxes[g]
__device__ __forceinline__ void decode_box(unsigned i, double xmax, double ymax,
                                           const float* __restrict__ bbox,
                                           float4* __restrict__ boxes, unsigned g) {
    int a = (int)(i % AA);
    int hw = (int)(i / AA);
    int h = hw >> 7, w = hw & 127;
    double sx = 16.0 * w, sy = 16.0 * h;
    double ax1 = (double)c_ax1[a] + sx, ay1 = (double)c_ay1[a] + sy;
    double ax2 = (double)c_ax2[a] + sx, ay2 = (double)c_ay2[a] + sy;
    double aw = ax2 - ax1 + 1.0, ah = ay2 - ay1 + 1.0;
    double acx = ax1 + 0.5 * aw, acy = ay1 + 0.5 * ah;
    int bse = h * WW + w;
    double d0 = (double)bbox[(4 * a + 0) * HWH + bse];
    double d1 = (double)bbox[(4 * a + 1) * HWH + bse];
    double d2 = (double)bbox[(4 * a + 2) * HWH + bse];
    double d3 = (double)bbox[(4 * a + 3) * HWH + bse];
    double pcx = d0 * aw + acx, pcy = d1 * ah + acy;
    double pw = exp(d2) * aw, ph = exp(d3) * ah;
    double x1 = fmin(fmax(pcx - 0.5 * pw, 0.0), xmax);
    double y1 = fmin(fmax(pcy - 0.5 * ph, 0.0), ymax);
    double x2 = fmin(fmax(pcx + 0.5 * pw, 0.0), xmax);
    double y2 = fmin(fmax(pcy + 0.5 * ph, 0.0), ymax);
    boxes[g] = make_float4((float)x1, (float)y1, (float)x2, (float)y2);
}

// 1) SINGLE-BLOCK front: LDS hist + findbin + gather + WAVE-PARALLEL RANK-SORT
//    + decode, all fused (in-block syncs only; no cross-block coordination).
__global__ __launch_bounds__(1024) void k_front1(const float* __restrict__ scores,
                                                 const float* __restrict__ bbox,
                                                 const float* __restrict__ im_info,
                                                 unsigned* __restrict__ histG,
                                                 unsigned* __restrict__ binB,
                                                 unsigned* __restrict__ binStart,
                                                 unsigned* __restrict__ activeList,
                                                 unsigned* __restrict__ nact,
                                                 unsigned long long* __restrict__ selKeys,
                                                 float4* __restrict__ boxes) {
    __shared__ __align__(16) unsigned char smemBuf[NBIN * 4 + 4096];  // hloc | seg
    __shared__ unsigned Bsh;
    __shared__ unsigned bigList[64];
    __shared__ unsigned nbig;
    unsigned* hloc = (unsigned*)smemBuf;            // 64 KiB: counts -> cursors -> skb
    unsigned* seg = (unsigned*)(smemBuf + NBIN * 4);
    int t = threadIdx.x;
    if (t == 0) { *nact = 0; nbig = 0; }
#pragma unroll
    for (int k = 0; k < NBIN / 1024; ++k) hloc[t + k * 1024] = 0;
    __syncthreads();
    // ---- Phase A: histogram ----
    for (int g = t; g < KK / 4; g += 1024) {
        float4 v = ((const float4*)(scores + AA * HWH))[g];
        atomicAdd(&hloc[key_bin(score_key(v.x))], 1u);
        atomicAdd(&hloc[key_bin(score_key(v.y))], 1u);
        atomicAdd(&hloc[key_bin(score_key(v.z))], 1u);
        atomicAdd(&hloc[key_bin(score_key(v.w))], 1u);
    }
    __syncthreads();

    // ---- Phase B: findbin over 16K bins (from LDS) ----
    unsigned local[16];
    unsigned ssum = 0;
#pragma unroll
    for (int k = 0; k < 16; ++k) { local[k] = hloc[t * 16 + k]; ssum += local[k]; }
    seg[t] = ssum;
    __syncthreads();
    for (int off = 1; off < 1024; off <<= 1) {
        unsigned v = seg[t];
        unsigned add = (t + off < 1024) ? seg[t + off] : 0u;
        __syncthreads();
        seg[t] = v + add;
        __syncthreads();
    }
    unsigned above = (t + 1 < 1024) ? seg[t + 1] : 0u;
    if (above < NSEL && above + ssum >= NSEL) {
        unsigned acc = above;
#pragma unroll
        for (int b = 15; b >= 0; --b) {
            acc += local[b];
            if (acc >= NSEL) { Bsh = (unsigned)(t * 16 + b); *binB = Bsh; break; }
        }
    }
    __syncthreads();
    unsigned B = Bsh;
    // ---- Phase C: publish per-active-bin base/count; hloc becomes cursor ----
    if ((unsigned)(t * 16 + 15) >= B) {
        unsigned acc2 = above;
        for (int k = 15; k >= 0; --k) {
            unsigned bin = (unsigned)(t * 16 + k);
            if (bin < B) break;
            if (local[k] > 0) {
                binStart[bin] = acc2;
                histG[bin] = local[k];
                hloc[bin] = acc2;           // LDS allocation cursor
                unsigned tick = atomicAdd(nact, 1u);
                if (tick < 8192) activeList[tick] = bin;
            }
            acc2 += local[k];
        }
    }
    __syncthreads();

    // ---- Phase D: gather (L2-hot re-read; LDS cursor atomics) ----
    for (int g = t; g < KK / 4; g += 1024) {
        float4 v = ((const float4*)(scores + AA * HWH))[g];
        float sv[4] = {v.x, v.y, v.z, v.w};
#pragma unroll
        for (int k = 0; k < 4; ++k) {
            int j = g * 4 + k;
            unsigned key = score_key(sv[k]);
            unsigned bin = (unsigned)key_bin(key);
            if (bin >= B) {
                int a = j / HWH;
                int hw = j - a * HWH;
                unsigned i = (unsigned)(hw * AA + a);  // anchor-order index (tie-break)
                unsigned pos = atomicAdd(&hloc[bin], 1u);
                if (pos < SELCAP)
                    selKeys[pos] = ((unsigned long long)key << 32) | (unsigned)(~i);
            }
        }
    }
    __syncthreads();   // Phase D complete; hloc region now free -> skb segments

    // ---- Phase E: wave-parallel rank-sort + decode (one bin per wave) ----
    // rank(key) = #{j in bin : key_j > key}  (keys unique via idx tie-break)
    double xmax = (double)im_info[1] - 1.0, ymax = (double)im_info[0] - 1.0;
    unsigned na = *nact;
    if (na > 8192) na = 8192;
    int wave = t >> 6, lane = t & 63;
    unsigned long long* skbAll = (unsigned long long*)smemBuf;   // 8192 u64
    unsigned long long* skb = skbAll + wave * 512;               // per-wave 512
    for (unsigned aIdx = (unsigned)wave; aIdx < na; aIdx += 16) {
        unsigned bin = activeList[aIdx];
        unsigned n = histG[bin];
        unsigned base = binStart[bin];
        if (n > 512) {
            if (lane == 0) {
                unsigned p = atomicAdd(&nbig, 1u);
                if (p < 64) bigList[p] = aIdx;
            }
            continue;
        }
        for (unsigned p = lane; p < n; p += 64) skb[p] = selKeys[base + p];
        asm volatile("s_waitcnt lgkmcnt(0)" ::: "memory");  // wave-local LDS visibility
        for (unsigned r = lane; r < n; r += 64) {
            unsigned long long key = skb[r];
            unsigned rank = 0;
            for (unsigned j = 0; j < n; ++j) rank += (skb[j] > key) ? 1u : 0u;
            unsigned g = base + rank;
            if (g < NSEL) decode_box(~(unsigned)(key & 0xFFFFFFFFull), xmax, ymax, bbox, boxes, g);
        }
    }
    __syncthreads();
    // ---- fallback for bins with n > 512 (not expected on this data) ----
    unsigned nb = nbig;
    if (nb > 64) nb = 64;
    for (unsigned b = 0; b < nb; ++b) {
        unsigned aIdx = bigList[b];
        unsigned bin = activeList[aIdx];
        unsigned n = histG[bin];
        if (n > 8192) n = 8192;
        unsigned base = binStart[bin];
        for (unsigned p = t; p < n; p += 1024) skbAll[p] = selKeys[base + p];
        __syncthreads();
        for (unsigned r = t; r < n; r += 1024) {
            unsigned long long key = skbAll[r];
            unsigned rank = 0;
            for (unsigned j = 0; j < n; ++j) rank += (skbAll[j] > key) ? 1u : 0u;
            unsigned g = base + rank;
            if (g < NSEL) decode_box(~(unsigned)(key & 0xFFFFFFFFull), xmax, ymax, bbox, boxes, g);
        }
        __syncthreads();
    }
}

// 2) suppression bitmask, BIT-TRANSPOSED store for all tiles:
//    supT[rc][cc*64+j] bit k = box (rc*64+k) suppresses box (cc*64+j), rc<=cc.
__global__ __launch_bounds__(256) void k_mask(const float4* __restrict__ boxes,
                                              unsigned long long* __restrict__ supT) {
    __shared__ float4 cb[4][64];
    int wave = threadIdx.x >> 6, lane = threadIdx.x & 63;
    for (int L = blockIdx.x * 4 + wave; L < NTRI; L += MASK_BLOCKS * 4) {
        int rc = 0, rem = L;
        while (rem >= NCH - rc) { rem -= NCH - rc; rc++; }
        int cc = rc + rem;
        cb[wave][lane] = boxes[cc * 64 + lane];
        int gi = rc * 64 + lane;
        unsigned long long bits = 0ull;
        if (gi < NSEL) {
            float4 rb = boxes[gi];
            double rx1 = rb.x, ry1 = rb.y, rx2 = rb.z, ry2 = rb.w;
            double rarea = (rx2 - rx1 + 1.0) * (ry2 - ry1 + 1.0);
            for (int j = 0; j < 64; ++j) {
                int gj = cc * 64 + j;
                float4 c = cb[wave][j];
                double iw = fmin(rx2, (double)c.z) - fmax(rx1, (double)c.x) + 1.0;
                double ih = fmin(ry2, (double)c.w) - fmax(ry1, (double)c.y) + 1.0;
                if (gj > gi && gj < NSEL && iw > 0.0 && ih > 0.0) {
                    double inter = iw * ih;
                    double carea = ((double)c.z - (double)c.x + 1.0) * ((double)c.w - (double)c.y + 1.0);
                    double uni = rarea + carea - inter;
                    if (inter > NMS_T * uni) bits |= (1ull << j);
                }
            }
        }
        // transpose 64x64 tile via ballots: word[lane=j] bit k = row k suppresses col j
        unsigned long long myword = 0ull;
        for (int j = 0; j < 64; ++j) {
            unsigned long long bal = __ballot((int)((bits >> j) & 1ull));
            if (lane == j) myword = bal;
        }
        supT[(size_t)rc * NPAD + cc * 64 + lane] = myword;
    }
}

// 3) greedy NMS, gather form, 8 waves, LDS-staged diag words, FIXPOINT scan,
//    wave0 setprio, issue-early/wait-late + light barriers.
__global__ __launch_bounds__(512, 1) void k_nms(const unsigned long long* __restrict__ supT,
                                                const float4* __restrict__ boxes,
                                                float4* __restrict__ out) {
    __shared__ unsigned long long colLds[NCH][64];   // 48128 B: transposed diag words
    __shared__ unsigned long long removed[NCH];
    __shared__ unsigned long long aliveArr[NCH];
    __shared__ int cstop;
    __shared__ unsigned scanBuf[8];
    int t = threadIdx.x;
    int wave = t >> 6, lane = t & 63;

    for (int c = wave; c < NCH; c += 8)
        colLds[c][lane] = supT[(size_t)c * NPAD + c * 64 + lane];
    for (int i = t; i < NCH; i += 512) removed[i] = (i == NCH - 1) ? 0xFFFF000000000000ull : 0ull;
    if (t == 0) cstop = -1;
    __syncthreads();
    if (wave == 0) __builtin_amdgcn_s_setprio(1);

    unsigned long long wAA = 0, wAB = 0;   // wave0 super-diag dbuf
    unsigned long long mA[8], mB[8];       // waves1-7 gather dbuf
#pragma unroll
    for (int q = 0; q < 8; ++q) { mA[q] = 0; mB[q] = 0; }
    if (wave == 0) wAA = supT[(size_t)0 * NPAD + 1 * 64 + lane];
    unsigned keptTot = 0;

    for (int c = 0; c < NCH; c += 2) {
        if (wave == 0) {
            if (c + 2 < NCH) wAB = supT[(size_t)(c + 1) * NPAD + (c + 2) * 64 + lane];
            unsigned long long alive_in = ~removed[c];
            unsigned long long alive = chunk_scan_fix(colLds[c][lane], alive_in);
            keptTot += (unsigned)__popcll(alive);
            if (lane == 0) {
                removed[c] = ~alive;
                aliveArr[c] = alive;
                if (keptTot >= NOUT) cstop = c;
            }
            if (c + 1 < NCH) {
                unsigned long long ball = __ballot((int)((wAA & alive) != 0ull));
                if (lane == 0 && ball) atomicOr(&removed[c + 1], ball);
            }
        } else {
            if (c + 2 < NCH) {
#pragma unroll
                for (int q = 0; q < 8; ++q) {
                    int cp = (wave - 1) + 7 * q;
                    mB[q] = (cp < c + 1) ? supT[(size_t)cp * NPAD + (c + 2) * 64 + lane] : 0ull;
                }
            }
            if (c + 1 < NCH) {
                unsigned long long acc = 0ull;
#pragma unroll
                for (int q = 0; q < 8; ++q) {
                    int cp = (wave - 1) + 7 * q;
                    if (cp < c) acc |= __ballot((int)((mA[q] & aliveArr[cp]) != 0ull));
                }
                for (int cp = (wave - 1) + 56; cp < c; cp += 7) {
                    unsigned long long wv = supT[(size_t)cp * NPAD + (c + 1) * 64 + lane];
                    acc |= __ballot((int)((wv & aliveArr[cp]) != 0ull));
                }
                if (lane == 0 && acc) atomicOr(&removed[c + 1], acc);
            }
        }
        LBAR();
        if (cstop >= 0) break;
        if (c + 1 >= NCH) break;

        if (wave == 0) {
            if (c + 3 < NCH) wAA = supT[(size_t)(c + 2) * NPAD + (c + 3) * 64 + lane];
            unsigned long long alive_in = ~removed[c + 1];
            unsigned long long alive = chunk_scan_fix(colLds[c + 1][lane], alive_in);
            keptTot += (unsigned)__popcll(alive);
            if (lane == 0) {
                removed[c + 1] = ~alive;
                aliveArr[c + 1] = alive;
                if (keptTot >= NOUT) cstop = c + 1;
            }
            if (c + 2 < NCH) {
                unsigned long long ball = __ballot((int)((wAB & alive) != 0ull));
                if (lane == 0 && ball) atomicOr(&removed[c + 2], ball);
            }
        } else {
            if (c + 3 < NCH) {
#pragma unroll
                for (int q = 0; q < 8; ++q) {
                    int cp = (wave - 1) + 7 * q;
                    mA[q] = (cp < c + 2) ? supT[(size_t)cp * NPAD + (c + 3) * 64 + lane] : 0ull;
                }
            }
            if (c + 2 < NCH) {
                unsigned long long acc = 0ull;
#pragma unroll
                for (int q = 0; q < 8; ++q) {
                    int cp = (wave - 1) + 7 * q;
                    if (cp < c + 1) acc |= __ballot((int)((mB[q] & aliveArr[cp]) != 0ull));
                }
                for (int cp = (wave - 1) + 56; cp < c + 1; cp += 7) {
                    unsigned long long wv = supT[(size_t)cp * NPAD + (c + 2) * 64 + lane];
                    acc |= __ballot((int)((wv & aliveArr[cp]) != 0ull));
                }
                if (lane == 0 && acc) atomicOr(&removed[c + 2], acc);
            }
        }
        LBAR();
        if (cstop >= 0) break;
    }
    if (wave == 0) __builtin_amdgcn_s_setprio(0);
    __syncthreads();

    // stable compaction: kept (index asc) then suppressed (index asc), first 1000.
    int base = t * 12;
    unsigned cnt = 0, keepbits = 0;
    for (int q = 0; q < 12; ++q) {
        int i = base + q;
        if (i < NSEL) {
            bool kp = !((removed[i >> 6] >> (i & 63)) & 1ull);
            if (kp) { cnt++; keepbits |= (1u << q); }
        }
    }
    unsigned v = cnt;
#pragma unroll
    for (int off = 1; off < 64; off <<= 1) {
        unsigned u = (unsigned)__shfl_up((int)v, off, 64);
        if (lane >= off) v += u;
    }
    if (lane == 63) scanBuf[wave] = v;
    __syncthreads();
    unsigned waveOff = 0, NK = 0;
#pragma unroll
    for (int ww = 0; ww < 8; ++ww) {
        unsigned wv = scanBuf[ww];
        if (ww < wave) waveOff += wv;
        NK += wv;
    }
    unsigned incl = waveOff + v;
    unsigned kpos = incl - cnt;
    for (int q = 0; q < 12; ++q) {
        int i = base + q;
        if (i < NSEL) {
            bool kp = (keepbits >> q) & 1u;
            unsigned pos = kp ? kpos : (NK + (unsigned)i - kpos);
            if (kp) kpos++;
            if (pos < NOUT) out[pos] = boxes[i];
        }
    }
}

extern "C" void kernel_launch(void* const* d_in, const int* in_sizes, int n_in,
                              void* d_out, int out_size, void* d_ws, size_t ws_size,
                              hipStream_t stream) {
    const float* scores = (const float*)d_in[0];
    const float* bbox = (const float*)d_in[1];
    const float* im_info = (const float*)d_in[2];
    char* ws = (char*)d_ws;

    unsigned* histG = (unsigned*)(ws + WS_HIST);
    unsigned* binB = (unsigned*)(ws + WS_BINB);
    unsigned* nact = (unsigned*)(ws + WS_NACT);
    unsigned* activeList = (unsigned*)(ws + WS_ACTIVE);
    unsigned* binStart = (unsigned*)(ws + WS_BINSTART);
    unsigned long long* selKeys = (unsigned long long*)(ws + WS_SELKEYS);
    float4* boxes = (float4*)(ws + WS_BOXES);
    unsigned long long* supT = (unsigned long long*)(ws + WS_MASK);
    float4* out = (float4*)d_out;

    k_front1<<<1, 1024, 0, stream>>>(scores, bbox, im_info, histG, binB, binStart,
                                     activeList, nact, selKeys, boxes);
    k_mask<<<MASK_BLOCKS, 256, 0, stream>>>(boxes, supT);
    k_nms<<<1, 512, 0, stream>>>(supT, boxes, out);
}

// Round 22
// 96.680 us; speedup vs baseline: 3.0412x; 3.0412x over previous
//
#include <hip/hip_runtime.h>
#include <cstdint>

#define HH 76
#define WW 128
#define AA 9
#define HWH (HH * WW)          // 9728
#define KK (HWH * AA)          // 87552
#define NSEL 6000
#define NCH 94                 // ceil(6000/64)
#define NPAD (NCH * 64)        // 6016
#define NOUT 1000
#define NMS_T 0.7
#define NTRI (NCH * (NCH + 1) / 2)  // 4465 upper-tri tiles
#define MASK_BLOCKS 1117            // ceil(NTRI/4), 4 waves/block
#define SELCAP 16384
#define BINCAP 2048
#define NBIN 16384                  // key>>16 - 0x8000 bin space (scores in [0,2))

// light barrier: order LDS, but DO NOT drain vmcnt (global prefetch stays in flight)
#define LBAR() asm volatile("s_waitcnt lgkmcnt(0)\n\ts_barrier" ::: "memory")

// ---- workspace layout (bytes) ---- (NO zeroing: all control state written
// in-kernel before use each launch)
#define WS_HIST 0              // u32[16384] per-bin counts, ACTIVE BINS ONLY
#define WS_BINB 65536          // u32 threshold bin
#define WS_NACT 65540          // u32 active-bin count
#define WS_ACTIVE 65552        // u32[8192] active bin list
#define WS_BINSTART 98320      // u32[16384] rank base per bin (active only)
#define WS_SELKEYS 163856      // u64[16384]
#define WS_BOXES 294928        // float4[6016] (16-aligned)
#define WS_MASK 391184         // u64 supT[NCH][NPAD]: supT[c][j] bit k = (c*64+k) suppresses j

// base anchors from generate_anchors() (numpy fp64, exact small values)
__device__ __constant__ float c_ax1[9] = {-84.f, -176.f, -360.f, -56.f, -120.f, -248.f, -36.f, -80.f, -168.f};
__device__ __constant__ float c_ay1[9] = {-40.f, -88.f, -184.f, -56.f, -120.f, -248.f, -80.f, -168.f, -344.f};
__device__ __constant__ float c_ax2[9] = {99.f, 191.f, 375.f, 71.f, 135.f, 263.f, 51.f, 95.f, 183.f};
__device__ __constant__ float c_ay2[9] = {55.f, 103.f, 199.f, 71.f, 135.f, 263.f, 95.f, 183.f, 359.f};

__device__ __forceinline__ unsigned score_key(float s) {
    unsigned u = __float_as_uint(s);
    return (u & 0x80000000u) ? ~u : (u | 0x80000000u);
}

// monotone bucketing into 16K bins (exact for scores in [0,2); clamped ends stay order-valid)
__device__ __forceinline__ int key_bin(unsigned key) {
    int bi = (int)(key >> 16) - 0x8000;
    return bi < 0 ? 0 : (bi > NBIN - 1 ? NBIN - 1 : bi);
}

// intra-chunk greedy via Jacobi fixpoint: converges in chain-depth+1 passes
// (typ. 3-5), one ballot per pass. Unique fixpoint == greedy order.
__device__ __forceinline__ unsigned long long chunk_scan_fix(unsigned long long col,
                                                             unsigned long long alive_in) {
    unsigned long long kept = alive_in;
    while (true) {
        unsigned long long sup = __ballot((int)((col & kept) != 0ull));
        unsigned long long kept2 = alive_in & ~sup;
        if (kept2 == kept) return kept;
        kept = kept2;
    }
}

// 1) SINGLE-BLOCK front: LDS hist + findbin + GATHER (LDS cursors), fused.
__global__ __launch_bounds__(1024) void k_front1(const float* __restrict__ scores,
                                                 unsigned* __restrict__ histG,
                                                 unsigned* __restrict__ binB,
                                                 unsigned* __restrict__ binStart,
                                                 unsigned* __restrict__ activeList,
                                                 unsigned* __restrict__ nact,
                                                 unsigned long long* __restrict__ selKeys) {
    __shared__ unsigned hloc[NBIN];   // 64 KiB: counts, then alloc cursors
    __shared__ unsigned seg[1024];
    __shared__ unsigned Bsh;
    int t = threadIdx.x;
    if (t == 0) *nact = 0;
#pragma unroll
    for (int k = 0; k < NBIN / 1024; ++k) hloc[t + k * 1024] = 0;
    __syncthreads();
    // ---- Phase A: histogram ----
    for (int g = t; g < KK / 4; g += 1024) {
        float4 v = ((const float4*)(scores + AA * HWH))[g];
        atomicAdd(&hloc[key_bin(score_key(v.x))], 1u);
        atomicAdd(&hloc[key_bin(score_key(v.y))], 1u);
        atomicAdd(&hloc[key_bin(score_key(v.z))], 1u);
        atomicAdd(&hloc[key_bin(score_key(v.w))], 1u);
    }
    __syncthreads();

    // ---- Phase B: findbin over 16K bins (from LDS) ----
    unsigned local[16];
    unsigned ssum = 0;
#pragma unroll
    for (int k = 0; k < 16; ++k) { local[k] = hloc[t * 16 + k]; ssum += local[k]; }
    seg[t] = ssum;
    __syncthreads();
    for (int off = 1; off < 1024; off <<= 1) {
        unsigned v = seg[t];
        unsigned add = (t + off < 1024) ? seg[t + off] : 0u;
        __syncthreads();
        seg[t] = v + add;
        __syncthreads();
    }
    unsigned above = (t + 1 < 1024) ? seg[t + 1] : 0u;
    if (above < NSEL && above + ssum >= NSEL) {
        unsigned acc = above;
#pragma unroll
        for (int b = 15; b >= 0; --b) {
            acc += local[b];
            if (acc >= NSEL) { Bsh = (unsigned)(t * 16 + b); *binB = Bsh; break; }
        }
    }
    __syncthreads();
    unsigned B = Bsh;
    // ---- Phase C: publish per-active-bin base/count; hloc becomes cursor ----
    if ((unsigned)(t * 16 + 15) >= B) {
        unsigned acc2 = above;
        for (int k = 15; k >= 0; --k) {
            unsigned bin = (unsigned)(t * 16 + k);
            if (bin < B) break;
            if (local[k] > 0) {
                binStart[bin] = acc2;       // rank base (for binsort)
                histG[bin] = local[k];      // count (for binsort)
                hloc[bin] = acc2;           // LDS allocation cursor (for gather)
                unsigned tick = atomicAdd(nact, 1u);
                if (tick < 8192) activeList[tick] = bin;
            }
            acc2 += local[k];
        }
    }
    __syncthreads();

    // ---- Phase D: gather (L2-hot re-read; LDS cursor atomics) ----
    for (int g = t; g < KK / 4; g += 1024) {
        float4 v = ((const float4*)(scores + AA * HWH))[g];
        float sv[4] = {v.x, v.y, v.z, v.w};
#pragma unroll
        for (int k = 0; k < 4; ++k) {
            int j = g * 4 + k;
            unsigned key = score_key(sv[k]);
            unsigned bin = (unsigned)key_bin(key);
            if (bin >= B) {
                int a = j / HWH;
                int hw = j - a * HWH;
                unsigned i = (unsigned)(hw * AA + a);  // anchor-order index (tie-break)
                unsigned pos = atomicAdd(&hloc[bin], 1u);
                if (pos < SELCAP)
                    selKeys[pos] = ((unsigned long long)key << 32) | (unsigned)(~i);
            }
        }
    }
}

// 2) per-bin bitonic sort (descending) + fused fp64 decode/clip into boxes[rank]
__global__ __launch_bounds__(256) void k_binsort(const unsigned* __restrict__ histG,
                                                 const unsigned* __restrict__ binStart,
                                                 const unsigned* __restrict__ activeList,
                                                 const unsigned* __restrict__ nact,
                                                 unsigned long long* __restrict__ selKeys,
                                                 const float* __restrict__ bbox,
                                                 const float* __restrict__ im_info,
                                                 float4* __restrict__ boxes) {
    __shared__ unsigned long long sk[BINCAP];
    int t = threadIdx.x;
    unsigned na = *nact;
    if (na > 8192) na = 8192;
    double xmax = (double)im_info[1] - 1.0, ymax = (double)im_info[0] - 1.0;
    for (unsigned aIdx = blockIdx.x; aIdx < na; aIdx += gridDim.x) {
        unsigned bin = activeList[aIdx];
        unsigned ntot = histG[bin];
        unsigned base = binStart[bin];
        unsigned n = ntot > BINCAP ? BINCAP : ntot;
        unsigned m = 64; while (m < n) m <<= 1;
        for (unsigned p = t; p < m; p += 256) sk[p] = (p < n) ? selKeys[base + p] : 0ull;
        __syncthreads();
        for (unsigned size = 2; size <= m; size <<= 1) {
            for (unsigned stride = size >> 1; stride > 0; stride >>= 1) {
                for (unsigned p = (unsigned)t; p < m / 2; p += 256) {
                    unsigned i = 2u * p - (p & (stride - 1u));
                    unsigned j = i + stride;
                    bool up = (i & size) != 0;
                    unsigned long long a = sk[i], b = sk[j];
                    bool doswap = up ? (a > b) : (a < b);
                    if (doswap) { sk[i] = b; sk[j] = a; }
                }
                __syncthreads();
            }
        }
        for (unsigned r = t; r < n; r += 256) {
            unsigned g = base + r;
            if (g >= NSEL) continue;
            unsigned i = ~(unsigned)(sk[r] & 0xFFFFFFFFull);
            int a = (int)(i % AA);
            int hw = (int)(i / AA);
            int h = hw >> 7, w = hw & 127;
            double sx = 16.0 * w, sy = 16.0 * h;
            double ax1 = (double)c_ax1[a] + sx, ay1 = (double)c_ay1[a] + sy;
            double ax2 = (double)c_ax2[a] + sx, ay2 = (double)c_ay2[a] + sy;
            double aw = ax2 - ax1 + 1.0, ah = ay2 - ay1 + 1.0;
            double acx = ax1 + 0.5 * aw, acy = ay1 + 0.5 * ah;
            int bse = h * WW + w;
            double d0 = (double)bbox[(4 * a + 0) * HWH + bse];
            double d1 = (double)bbox[(4 * a + 1) * HWH + bse];
            double d2 = (double)bbox[(4 * a + 2) * HWH + bse];
            double d3 = (double)bbox[(4 * a + 3) * HWH + bse];
            double pcx = d0 * aw + acx, pcy = d1 * ah + acy;
            double pw = exp(d2) * aw, ph = exp(d3) * ah;
            double x1 = fmin(fmax(pcx - 0.5 * pw, 0.0), xmax);
            double y1 = fmin(fmax(pcy - 0.5 * ph, 0.0), ymax);
            double x2 = fmin(fmax(pcx + 0.5 * pw, 0.0), xmax);
            double y2 = fmin(fmax(pcy + 0.5 * ph, 0.0), ymax);
            boxes[g] = make_float4((float)x1, (float)y1, (float)x2, (float)y2);
        }
        __syncthreads();
    }
}

// 3) suppression bitmask, BIT-TRANSPOSED store for all tiles:
//    supT[rc][cc*64+j] bit k = box (rc*64+k) suppresses box (cc*64+j), rc<=cc.
__global__ __launch_bounds__(256) void k_mask(const float4* __restrict__ boxes,
                                              unsigned long long* __restrict__ supT) {
    __shared__ float4 cb[4][64];
    int wave = threadIdx.x >> 6, lane = threadIdx.x & 63;
    for (int L = blockIdx.x * 4 + wave; L < NTRI; L += MASK_BLOCKS * 4) {
        int rc = 0, rem = L;
        while (rem >= NCH - rc) { rem -= NCH - rc; rc++; }
        int cc = rc + rem;
        cb[wave][lane] = boxes[cc * 64 + lane];
        int gi = rc * 64 + lane;
        unsigned long long bits = 0ull;
        if (gi < NSEL) {
            float4 rb = boxes[gi];
            double rx1 = rb.x, ry1 = rb.y, rx2 = rb.z, ry2 = rb.w;
            double rarea = (rx2 - rx1 + 1.0) * (ry2 - ry1 + 1.0);
            for (int j = 0; j < 64; ++j) {
                int gj = cc * 64 + j;
                float4 c = cb[wave][j];
                double iw = fmin(rx2, (double)c.z) - fmax(rx1, (double)c.x) + 1.0;
                double ih = fmin(ry2, (double)c.w) - fmax(ry1, (double)c.y) + 1.0;
                if (gj > gi && gj < NSEL && iw > 0.0 && ih > 0.0) {
                    double inter = iw * ih;
                    double carea = ((double)c.z - (double)c.x + 1.0) * ((double)c.w - (double)c.y + 1.0);
                    double uni = rarea + carea - inter;
                    if (inter > NMS_T * uni) bits |= (1ull << j);
                }
            }
        }
        // transpose 64x64 tile via ballots: word[lane=j] bit k = row k suppresses col j
        unsigned long long myword = 0ull;
        for (int j = 0; j < 64; ++j) {
            unsigned long long bal = __ballot((int)((bits >> j) & 1ull));
            if (lane == j) myword = bal;
        }
        supT[(size_t)rc * NPAD + cc * 64 + lane] = myword;
    }
}

// 4) greedy NMS, gather form, 8 waves, LDS-staged diag words, FIXPOINT scan,
//    wave0 setprio, issue-early/wait-late + light barriers.
__global__ __launch_bounds__(512, 1) void k_nms(const unsigned long long* __restrict__ supT,
                                                const float4* __restrict__ boxes,
                                                float4* __restrict__ out) {
    __shared__ unsigned long long colLds[NCH][64];   // 48128 B: transposed diag words
    __shared__ unsigned long long removed[NCH];
    __shared__ unsigned long long aliveArr[NCH];
    __shared__ int cstop;
    __shared__ unsigned scanBuf[8];
    int t = threadIdx.x;
    int wave = t >> 6, lane = t & 63;

    for (int c = wave; c < NCH; c += 8)
        colLds[c][lane] = supT[(size_t)c * NPAD + c * 64 + lane];
    for (int i = t; i < NCH; i += 512) removed[i] = (i == NCH - 1) ? 0xFFFF000000000000ull : 0ull;
    if (t == 0) cstop = -1;
    __syncthreads();
    if (wave == 0) __builtin_amdgcn_s_setprio(1);

    unsigned long long wAA = 0, wAB = 0;   // wave0 super-diag dbuf
    unsigned long long mA[8], mB[8];       // waves1-7 gather dbuf
#pragma unroll
    for (int q = 0; q < 8; ++q) { mA[q] = 0; mB[q] = 0; }
    if (wave == 0) wAA = supT[(size_t)0 * NPAD + 1 * 64 + lane];
    unsigned keptTot = 0;

    for (int c = 0; c < NCH; c += 2) {
        if (wave == 0) {
            if (c + 2 < NCH) wAB = supT[(size_t)(c + 1) * NPAD + (c + 2) * 64 + lane];
            unsigned long long alive_in = ~removed[c];
            unsigned long long alive = chunk_scan_fix(colLds[c][lane], alive_in);
            keptTot += (unsigned)__popcll(alive);
            if (lane == 0) {
                removed[c] = ~alive;
                aliveArr[c] = alive;
                if (keptTot >= NOUT) cstop = c;
            }
            if (c + 1 < NCH) {
                unsigned long long ball = __ballot((int)((wAA & alive) != 0ull));
                if (lane == 0 && ball) atomicOr(&removed[c + 1], ball);
            }
        } else {
            if (c + 2 < NCH) {
#pragma unroll
                for (int q = 0; q < 8; ++q) {
                    int cp = (wave - 1) + 7 * q;
                    mB[q] = (cp < c + 1) ? supT[(size_t)cp * NPAD + (c + 2) * 64 + lane] : 0ull;
                }
            }
            if (c + 1 < NCH) {
                unsigned long long acc = 0ull;
#pragma unroll
                for (int q = 0; q < 8; ++q) {
                    int cp = (wave - 1) + 7 * q;
                    if (cp < c) acc |= __ballot((int)((mA[q] & aliveArr[cp]) != 0ull));
                }
                for (int cp = (wave - 1) + 56; cp < c; cp += 7) {
                    unsigned long long wv = supT[(size_t)cp * NPAD + (c + 1) * 64 + lane];
                    acc |= __ballot((int)((wv & aliveArr[cp]) != 0ull));
                }
                if (lane == 0 && acc) atomicOr(&removed[c + 1], acc);
            }
        }
        LBAR();
        if (cstop >= 0) break;
        if (c + 1 >= NCH) break;

        if (wave == 0) {
            if (c + 3 < NCH) wAA = supT[(size_t)(c + 2) * NPAD + (c + 3) * 64 + lane];
            unsigned long long alive_in = ~removed[c + 1];
            unsigned long long alive = chunk_scan_fix(colLds[c + 1][lane], alive_in);
            keptTot += (unsigned)__popcll(alive);
            if (lane == 0) {
                removed[c + 1] = ~alive;
                aliveArr[c + 1] = alive;
                if (keptTot >= NOUT) cstop = c + 1;
            }
            if (c + 2 < NCH) {
                unsigned long long ball = __ballot((int)((wAB & alive) != 0ull));
                if (lane == 0 && ball) atomicOr(&removed[c + 2], ball);
            }
        } else {
            if (c + 3 < NCH) {
#pragma unroll
                for (int q = 0; q < 8; ++q) {
                    int cp = (wave - 1) + 7 * q;
                    mA[q] = (cp < c + 2) ? supT[(size_t)cp * NPAD + (c + 3) * 64 + lane] : 0ull;
                }
            }
            if (c + 2 < NCH) {
                unsigned long long acc = 0ull;
#pragma unroll
                for (int q = 0; q < 8; ++q) {
                    int cp = (wave - 1) + 7 * q;
                    if (cp < c + 1) acc |= __ballot((int)((mB[q] & aliveArr[cp]) != 0ull));
                }
                for (int cp = (wave - 1) + 56; cp < c + 1; cp += 7) {
                    unsigned long long wv = supT[(size_t)cp * NPAD + (c + 2) * 64 + lane];
                    acc |= __ballot((int)((wv & aliveArr[cp]) != 0ull));
                }
                if (lane == 0 && acc) atomicOr(&removed[c + 2], acc);
            }
        }
        LBAR();
        if (cstop >= 0) break;
    }
    if (wave == 0) __builtin_amdgcn_s_setprio(0);
    __syncthreads();

    // stable compaction: kept (index asc) then suppressed (index asc), first 1000.
    int base = t * 12;
    unsigned cnt = 0, keepbits = 0;
    for (int q = 0; q < 12; ++q) {
        int i = base + q;
        if (i < NSEL) {
            bool kp = !((removed[i >> 6] >> (i & 63)) & 1ull);
            if (kp) { cnt++; keepbits |= (1u << q); }
        }
    }
    unsigned v = cnt;
#pragma unroll
    for (int off = 1; off < 64; off <<= 1) {
        unsigned u = (unsigned)__shfl_up((int)v, off, 64);
        if (lane >= off) v += u;
    }
    if (lane == 63) scanBuf[wave] = v;
    __syncthreads();
    unsigned waveOff = 0, NK = 0;
#pragma unroll
    for (int ww = 0; ww < 8; ++ww) {
        unsigned wv = scanBuf[ww];
        if (ww < wave) waveOff += wv;
        NK += wv;
    }
    unsigned incl = waveOff + v;
    unsigned kpos = incl - cnt;
    for (int q = 0; q < 12; ++q) {
        int i = base + q;
        if (i < NSEL) {
            bool kp = (keepbits >> q) & 1u;
            unsigned pos = kp ? kpos : (NK + (unsigned)i - kpos);
            if (kp) kpos++;
            if (pos < NOUT) out[pos] = boxes[i];
        }
    }
}

extern "C" void kernel_launch(void* const* d_in, const int* in_sizes, int n_in,
                              void* d_out, int out_size, void* d_ws, size_t ws_size,
                              hipStream_t stream) {
    const float* scores = (const float*)d_in[0];
    const float* bbox = (const float*)d_in[1];
    const float* im_info = (const float*)d_in[2];
    char* ws = (char*)d_ws;

    unsigned* histG = (unsigned*)(ws + WS_HIST);
    unsigned* binB = (unsigned*)(ws + WS_BINB);
    unsigned* nact = (unsigned*)(ws + WS_NACT);
    unsigned* activeList = (unsigned*)(ws + WS_ACTIVE);
    unsigned* binStart = (unsigned*)(ws + WS_BINSTART);
    unsigned long long* selKeys = (unsigned long long*)(ws + WS_SELKEYS);
    float4* boxes = (float4*)(ws + WS_BOXES);
    unsigned long long* supT = (unsigned long long*)(ws + WS_MASK);
    float4* out = (float4*)d_out;

    k_front1<<<1, 1024, 0, stream>>>(scores, histG, binB, binStart, activeList, nact, selKeys);
    k_binsort<<<64, 256, 0, stream>>>(histG, binStart, activeList, nact, selKeys, bbox, im_info, boxes);
    k_mask<<<MASK_BLOCKS, 256, 0, stream>>>(boxes, supT);
    k_nms<<<1, 512, 0, stream>>>(supT, boxes, out);
}

// Round 23
// 95.347 us; speedup vs baseline: 3.0837x; 1.0140x over previous
//
#include <hip/hip_runtime.h>
#include <cstdint>

#define HH 76
#define WW 128
#define AA 9
#define HWH (HH * WW)          // 9728
#define KK (HWH * AA)          // 87552
#define NSEL 6000
#define NCH 94                 // ceil(6000/64)
#define NPAD (NCH * 64)        // 6016
#define NOUT 1000
#define NMS_T 0.7
#define NTRI (NCH * (NCH + 1) / 2)  // 4465 upper-tri tiles
#define MASK_BLOCKS 1117            // ceil(NTRI/4), 4 waves/block
#define SELCAP 16384
#define BINCAP 2048
#define NBIN 16384                  // key>>16 - 0x8000 bin space (scores in [0,2))

// light barrier: order LDS, but DO NOT drain vmcnt (global prefetch stays in flight)
#define LBAR() asm volatile("s_waitcnt lgkmcnt(0)\n\ts_barrier" ::: "memory")
#define LWAIT() asm volatile("s_waitcnt lgkmcnt(0)" ::: "memory")

// ---- workspace layout (bytes) ---- (NO zeroing: all control state written
// in-kernel before use each launch)
#define WS_HIST 0              // u32[16384] per-bin counts, ACTIVE BINS ONLY
#define WS_BINB 65536          // u32 threshold bin
#define WS_NACT 65540          // u32 active-bin count
#define WS_ACTIVE 65552        // u32[8192] active bin list
#define WS_BINSTART 98320      // u32[16384] rank base per bin (active only)
#define WS_SELKEYS 163856      // u64[16384]
#define WS_BOXES 294928        // float4[6016] (16-aligned)
#define WS_MASK 391184         // u64 supT[NCH][NPAD]: supT[c][j] bit k = (c*64+k) suppresses j

// base anchors from generate_anchors() (numpy fp64, exact small values)
__device__ __constant__ float c_ax1[9] = {-84.f, -176.f, -360.f, -56.f, -120.f, -248.f, -36.f, -80.f, -168.f};
__device__ __constant__ float c_ay1[9] = {-40.f, -88.f, -184.f, -56.f, -120.f, -248.f, -80.f, -168.f, -344.f};
__device__ __constant__ float c_ax2[9] = {99.f, 191.f, 375.f, 71.f, 135.f, 263.f, 51.f, 95.f, 183.f};
__device__ __constant__ float c_ay2[9] = {55.f, 103.f, 199.f, 71.f, 135.f, 263.f, 95.f, 183.f, 359.f};

__device__ __forceinline__ unsigned score_key(float s) {
    unsigned u = __float_as_uint(s);
    return (u & 0x80000000u) ? ~u : (u | 0x80000000u);
}

// monotone bucketing into 16K bins (exact for scores in [0,2); clamped ends stay order-valid)
__device__ __forceinline__ int key_bin(unsigned key) {
    int bi = (int)(key >> 16) - 0x8000;
    return bi < 0 ? 0 : (bi > NBIN - 1 ? NBIN - 1 : bi);
}

// intra-chunk greedy via Jacobi fixpoint: converges in chain-depth+1 passes
// (typ. 3-5), one ballot per pass. Unique fixpoint == greedy order.
__device__ __forceinline__ unsigned long long chunk_scan_fix(unsigned long long col,
                                                             unsigned long long alive_in) {
    unsigned long long kept = alive_in;
    while (true) {
        unsigned long long sup = __ballot((int)((col & kept) != 0ull));
        unsigned long long kept2 = alive_in & ~sup;
        if (kept2 == kept) return kept;
        kept = kept2;
    }
}

// 1) SINGLE-BLOCK front: LDS hist + findbin + GATHER (LDS cursors), fused.
__global__ __launch_bounds__(1024) void k_front1(const float* __restrict__ scores,
                                                 unsigned* __restrict__ histG,
                                                 unsigned* __restrict__ binB,
                                                 unsigned* __restrict__ binStart,
                                                 unsigned* __restrict__ activeList,
                                                 unsigned* __restrict__ nact,
                                                 unsigned long long* __restrict__ selKeys) {
    __shared__ unsigned hloc[NBIN];   // 64 KiB: counts, then alloc cursors
    __shared__ unsigned seg[1024];
    __shared__ unsigned Bsh;
    int t = threadIdx.x;
    if (t == 0) *nact = 0;
#pragma unroll
    for (int k = 0; k < NBIN / 1024; ++k) hloc[t + k * 1024] = 0;
    __syncthreads();
    // ---- Phase A: histogram ----
    for (int g = t; g < KK / 4; g += 1024) {
        float4 v = ((const float4*)(scores + AA * HWH))[g];
        atomicAdd(&hloc[key_bin(score_key(v.x))], 1u);
        atomicAdd(&hloc[key_bin(score_key(v.y))], 1u);
        atomicAdd(&hloc[key_bin(score_key(v.z))], 1u);
        atomicAdd(&hloc[key_bin(score_key(v.w))], 1u);
    }
    __syncthreads();

    // ---- Phase B: findbin over 16K bins (from LDS) ----
    unsigned local[16];
    unsigned ssum = 0;
#pragma unroll
    for (int k = 0; k < 16; ++k) { local[k] = hloc[t * 16 + k]; ssum += local[k]; }
    seg[t] = ssum;
    __syncthreads();
    for (int off = 1; off < 1024; off <<= 1) {
        unsigned v = seg[t];
        unsigned add = (t + off < 1024) ? seg[t + off] : 0u;
        __syncthreads();
        seg[t] = v + add;
        __syncthreads();
    }
    unsigned above = (t + 1 < 1024) ? seg[t + 1] : 0u;
    if (above < NSEL && above + ssum >= NSEL) {
        unsigned acc = above;
#pragma unroll
        for (int b = 15; b >= 0; --b) {
            acc += local[b];
            if (acc >= NSEL) { Bsh = (unsigned)(t * 16 + b); *binB = Bsh; break; }
        }
    }
    __syncthreads();
    unsigned B = Bsh;
    // ---- Phase C: publish per-active-bin base/count; hloc becomes cursor ----
    if ((unsigned)(t * 16 + 15) >= B) {
        unsigned acc2 = above;
        for (int k = 15; k >= 0; --k) {
            unsigned bin = (unsigned)(t * 16 + k);
            if (bin < B) break;
            if (local[k] > 0) {
                binStart[bin] = acc2;       // rank base (for binsort)
                histG[bin] = local[k];      // count (for binsort)
                hloc[bin] = acc2;           // LDS allocation cursor (for gather)
                unsigned tick = atomicAdd(nact, 1u);
                if (tick < 8192) activeList[tick] = bin;
            }
            acc2 += local[k];
        }
    }
    __syncthreads();

    // ---- Phase D: gather (L2-hot re-read; LDS cursor atomics) ----
    for (int g = t; g < KK / 4; g += 1024) {
        float4 v = ((const float4*)(scores + AA * HWH))[g];
        float sv[4] = {v.x, v.y, v.z, v.w};
#pragma unroll
        for (int k = 0; k < 4; ++k) {
            int j = g * 4 + k;
            unsigned key = score_key(sv[k]);
            unsigned bin = (unsigned)key_bin(key);
            if (bin >= B) {
                int a = j / HWH;
                int hw = j - a * HWH;
                unsigned i = (unsigned)(hw * AA + a);  // anchor-order index (tie-break)
                unsigned pos = atomicAdd(&hloc[bin], 1u);
                if (pos < SELCAP)
                    selKeys[pos] = ((unsigned long long)key << 32) | (unsigned)(~i);
            }
        }
    }
}

// 2) per-bin bitonic sort (descending) + fused fp64 decode/clip into boxes[rank]
__global__ __launch_bounds__(256) void k_binsort(const unsigned* __restrict__ histG,
                                                 const unsigned* __restrict__ binStart,
                                                 const unsigned* __restrict__ activeList,
                                                 const unsigned* __restrict__ nact,
                                                 unsigned long long* __restrict__ selKeys,
                                                 const float* __restrict__ bbox,
                                                 const float* __restrict__ im_info,
                                                 float4* __restrict__ boxes) {
    __shared__ unsigned long long sk[BINCAP];
    int t = threadIdx.x;
    unsigned na = *nact;
    if (na > 8192) na = 8192;
    double xmax = (double)im_info[1] - 1.0, ymax = (double)im_info[0] - 1.0;
    for (unsigned aIdx = blockIdx.x; aIdx < na; aIdx += gridDim.x) {
        unsigned bin = activeList[aIdx];
        unsigned ntot = histG[bin];
        unsigned base = binStart[bin];
        unsigned n = ntot > BINCAP ? BINCAP : ntot;
        unsigned m = 64; while (m < n) m <<= 1;
        for (unsigned p = t; p < m; p += 256) sk[p] = (p < n) ? selKeys[base + p] : 0ull;
        __syncthreads();
        for (unsigned size = 2; size <= m; size <<= 1) {
            for (unsigned stride = size >> 1; stride > 0; stride >>= 1) {
                for (unsigned p = (unsigned)t; p < m / 2; p += 256) {
                    unsigned i = 2u * p - (p & (stride - 1u));
                    unsigned j = i + stride;
                    bool up = (i & size) != 0;
                    unsigned long long a = sk[i], b = sk[j];
                    bool doswap = up ? (a > b) : (a < b);
                    if (doswap) { sk[i] = b; sk[j] = a; }
                }
                __syncthreads();
            }
        }
        for (unsigned r = t; r < n; r += 256) {
            unsigned g = base + r;
            if (g >= NSEL) continue;
            unsigned i = ~(unsigned)(sk[r] & 0xFFFFFFFFull);
            int a = (int)(i % AA);
            int hw = (int)(i / AA);
            int h = hw >> 7, w = hw & 127;
            double sx = 16.0 * w, sy = 16.0 * h;
            double ax1 = (double)c_ax1[a] + sx, ay1 = (double)c_ay1[a] + sy;
            double ax2 = (double)c_ax2[a] + sx, ay2 = (double)c_ay2[a] + sy;
            double aw = ax2 - ax1 + 1.0, ah = ay2 - ay1 + 1.0;
            double acx = ax1 + 0.5 * aw, acy = ay1 + 0.5 * ah;
            int bse = h * WW + w;
            double d0 = (double)bbox[(4 * a + 0) * HWH + bse];
            double d1 = (double)bbox[(4 * a + 1) * HWH + bse];
            double d2 = (double)bbox[(4 * a + 2) * HWH + bse];
            double d3 = (double)bbox[(4 * a + 3) * HWH + bse];
            double pcx = d0 * aw + acx, pcy = d1 * ah + acy;
            double pw = exp(d2) * aw, ph = exp(d3) * ah;
            double x1 = fmin(fmax(pcx - 0.5 * pw, 0.0), xmax);
            double y1 = fmin(fmax(pcy - 0.5 * ph, 0.0), ymax);
            double x2 = fmin(fmax(pcx + 0.5 * pw, 0.0), xmax);
            double y2 = fmin(fmax(pcy + 0.5 * ph, 0.0), ymax);
            boxes[g] = make_float4((float)x1, (float)y1, (float)x2, (float)y2);
        }
        __syncthreads();
    }
}

// 3) suppression bitmask, BIT-TRANSPOSED store for all tiles:
//    supT[rc][cc*64+j] bit k = box (rc*64+k) suppresses box (cc*64+j), rc<=cc.
__global__ __launch_bounds__(256) void k_mask(const float4* __restrict__ boxes,
                                              unsigned long long* __restrict__ supT) {
    __shared__ float4 cb[4][64];
    int wave = threadIdx.x >> 6, lane = threadIdx.x & 63;
    for (int L = blockIdx.x * 4 + wave; L < NTRI; L += MASK_BLOCKS * 4) {
        int rc = 0, rem = L;
        while (rem >= NCH - rc) { rem -= NCH - rc; rc++; }
        int cc = rc + rem;
        cb[wave][lane] = boxes[cc * 64 + lane];
        int gi = rc * 64 + lane;
        unsigned long long bits = 0ull;
        if (gi < NSEL) {
            float4 rb = boxes[gi];
            double rx1 = rb.x, ry1 = rb.y, rx2 = rb.z, ry2 = rb.w;
            double rarea = (rx2 - rx1 + 1.0) * (ry2 - ry1 + 1.0);
            for (int j = 0; j < 64; ++j) {
                int gj = cc * 64 + j;
                float4 c = cb[wave][j];
                double iw = fmin(rx2, (double)c.z) - fmax(rx1, (double)c.x) + 1.0;
                double ih = fmin(ry2, (double)c.w) - fmax(ry1, (double)c.y) + 1.0;
                if (gj > gi && gj < NSEL && iw > 0.0 && ih > 0.0) {
                    double inter = iw * ih;
                    double carea = ((double)c.z - (double)c.x + 1.0) * ((double)c.w - (double)c.y + 1.0);
                    double uni = rarea + carea - inter;
                    if (inter > NMS_T * uni) bits |= (1ull << j);
                }
            }
        }
        // transpose 64x64 tile via ballots: word[lane=j] bit k = row k suppresses col j
        unsigned long long myword = 0ull;
        for (int j = 0; j < 64; ++j) {
            unsigned long long bal = __ballot((int)((bits >> j) & 1ull));
            if (lane == j) myword = bal;
        }
        supT[(size_t)rc * NPAD + cc * 64 + lane] = myword;
    }
}

// 4) greedy NMS, gather form, 8 waves, TWO CHUNKS PER BARRIER:
//    wave0 scans e then (after its own e->o OR, same-wave lgkm wait) scans o,
//    and covers sources {e,o} for targets {e+2,e+3}; waves1-7 gather cp<e for
//    targets {e+2,e+3} with double-buffered prefetch. One LBAR per 2 chunks.
__global__ __launch_bounds__(512, 1) void k_nms(const unsigned long long* __restrict__ supT,
                                                const float4* __restrict__ boxes,
                                                float4* __restrict__ out) {
    __shared__ unsigned long long colLds[NCH][64];   // 48128 B: transposed diag words
    __shared__ unsigned long long removed[NCH];
    __shared__ unsigned long long aliveArr[NCH];
    __shared__ int cstop;
    __shared__ unsigned scanBuf[8];
    int t = threadIdx.x;
    int wave = t >> 6, lane = t & 63;

    for (int c = wave; c < NCH; c += 8)
        colLds[c][lane] = supT[(size_t)c * NPAD + c * 64 + lane];
    for (int i = t; i < NCH; i += 512) removed[i] = (i == NCH - 1) ? 0xFFFF000000000000ull : 0ull;
    if (t == 0) cstop = -1;
    __syncthreads();
    if (wave == 0) __builtin_amdgcn_s_setprio(1);

    // wave0 current-phase words (sources e,o -> targets o,e+2,e+3)
    unsigned long long w_eo = 0, w_e2 = 0, w_e3 = 0, w_o2 = 0, w_o3 = 0;
    // waves1-7 current-phase gather words (targets e+2, e+3), cp = (wave-1)+7q < e
    unsigned long long mA[8], mB[8];
#pragma unroll
    for (int q = 0; q < 8; ++q) { mA[q] = 0; mB[q] = 0; }
    if (wave == 0) {
        w_eo = supT[(size_t)0 * NPAD + 1 * 64 + lane];
        w_e2 = supT[(size_t)0 * NPAD + 2 * 64 + lane];
        w_e3 = supT[(size_t)0 * NPAD + 3 * 64 + lane];
        w_o2 = supT[(size_t)1 * NPAD + 2 * 64 + lane];
        w_o3 = supT[(size_t)1 * NPAD + 3 * 64 + lane];
    }
    unsigned keptTot = 0;

    for (int e = 0; e < NCH; e += 2) {
        int o = e + 1;
        if (wave == 0) {
            // ---- issue next-phase loads (e' = e+2) ----
            unsigned long long nw_eo = 0, nw_e2 = 0, nw_e3 = 0, nw_o2 = 0, nw_o3 = 0;
            if (e + 2 < NCH) {
                int e2 = e + 2, o2 = e + 3;
                nw_eo = supT[(size_t)e2 * NPAD + o2 * 64 + lane];
                nw_e2 = (e2 + 2 < NCH) ? supT[(size_t)e2 * NPAD + (e2 + 2) * 64 + lane] : 0ull;
                nw_e3 = (e2 + 3 < NCH) ? supT[(size_t)e2 * NPAD + (e2 + 3) * 64 + lane] : 0ull;
                nw_o2 = (e2 + 2 < NCH) ? supT[(size_t)o2 * NPAD + (e2 + 2) * 64 + lane] : 0ull;
                nw_o3 = (e2 + 3 < NCH) ? supT[(size_t)o2 * NPAD + (e2 + 3) * 64 + lane] : 0ull;
            }
            // ---- scan e (removed[e] final) ----
            unsigned long long alive_e = chunk_scan_fix(colLds[e][lane], ~removed[e]);
            keptTot += (unsigned)__popcll(alive_e);
            if (lane == 0) {
                removed[e] = ~alive_e;
                aliveArr[e] = alive_e;
                if (keptTot >= NOUT && cstop < 0) cstop = e;
            }
            // ---- e -> o contribution (wave0's own LDS atomic) ----
            {
                unsigned long long ball = __ballot((int)((w_eo & alive_e) != 0ull));
                if (lane == 0 && ball) atomicOr(&removed[o], ball);
            }
            LWAIT();  // same-wave RAW on removed[o]
            // ---- scan o (removed[o] now final: cp<e from prior phase + e just added) ----
            unsigned long long alive_o = chunk_scan_fix(colLds[o][lane], ~removed[o]);
            keptTot += (unsigned)__popcll(alive_o);
            if (lane == 0) {
                removed[o] = ~alive_o;
                aliveArr[o] = alive_o;
                if (keptTot >= NOUT && cstop < 0) cstop = o;
            }
            // ---- {e,o} -> {e+2, e+3} contributions ----
            if (e + 2 < NCH) {
                unsigned long long b1 = __ballot((int)((w_e2 & alive_e) != 0ull)) |
                                        __ballot((int)((w_o2 & alive_o) != 0ull));
                if (lane == 0 && b1) atomicOr(&removed[e + 2], b1);
            }
            if (e + 3 < NCH) {
                unsigned long long b2 = __ballot((int)((w_e3 & alive_e) != 0ull)) |
                                        __ballot((int)((w_o3 & alive_o) != 0ull));
                if (lane == 0 && b2) atomicOr(&removed[e + 3], b2);
            }
            w_eo = nw_eo; w_e2 = nw_e2; w_e3 = nw_e3; w_o2 = nw_o2; w_o3 = nw_o3;
        } else {
            // ---- issue next-phase prefetch (targets e+4, e+5; cp < e+2) ----
            unsigned long long nA[8], nB[8];
#pragma unroll
            for (int q = 0; q < 8; ++q) {
                int cp = (wave - 1) + 7 * q;
                nA[q] = (e + 4 < NCH && cp < e + 2) ? supT[(size_t)cp * NPAD + (e + 4) * 64 + lane] : 0ull;
                nB[q] = (e + 5 < NCH && cp < e + 2) ? supT[(size_t)cp * NPAD + (e + 5) * 64 + lane] : 0ull;
            }
            // ---- in-phase gather: target e+2 (mA), target e+3 (mB), cp < e ----
            if (e + 2 < NCH) {
                unsigned long long acc = 0ull;
#pragma unroll
                for (int q = 0; q < 8; ++q) {
                    int cp = (wave - 1) + 7 * q;
                    if (cp < e) acc |= __ballot((int)((mA[q] & aliveArr[cp]) != 0ull));
                }
                for (int cp = (wave - 1) + 56; cp < e; cp += 7) {  // beyond-horizon slow path
                    unsigned long long wv = supT[(size_t)cp * NPAD + (e + 2) * 64 + lane];
                    acc |= __ballot((int)((wv & aliveArr[cp]) != 0ull));
                }
                if (lane == 0 && acc) atomicOr(&removed[e + 2], acc);
            }
            if (e + 3 < NCH) {
                unsigned long long acc = 0ull;
#pragma unroll
                for (int q = 0; q < 8; ++q) {
                    int cp = (wave - 1) + 7 * q;
                    if (cp < e) acc |= __ballot((int)((mB[q] & aliveArr[cp]) != 0ull));
                }
                for (int cp = (wave - 1) + 56; cp < e; cp += 7) {
                    unsigned long long wv = supT[(size_t)cp * NPAD + (e + 3) * 64 + lane];
                    acc |= __ballot((int)((wv & aliveArr[cp]) != 0ull));
                }
                if (lane == 0 && acc) atomicOr(&removed[e + 3], acc);
            }
#pragma unroll
            for (int q = 0; q < 8; ++q) { mA[q] = nA[q]; mB[q] = nB[q]; }
        }
        LBAR();
        if (cstop >= 0) break;
    }
    if (wave == 0) __builtin_amdgcn_s_setprio(0);
    __syncthreads();

    // stable compaction: kept (index asc) then suppressed (index asc), first 1000.
    int base = t * 12;
    unsigned cnt = 0, keepbits = 0;
    for (int q = 0; q < 12; ++q) {
        int i = base + q;
        if (i < NSEL) {
            bool kp = !((removed[i >> 6] >> (i & 63)) & 1ull);
            if (kp) { cnt++; keepbits |= (1u << q); }
        }
    }
    unsigned v = cnt;
#pragma unroll
    for (int off = 1; off < 64; off <<= 1) {
        unsigned u = (unsigned)__shfl_up((int)v, off, 64);
        if (lane >= off) v += u;
    }
    if (lane == 63) scanBuf[wave] = v;
    __syncthreads();
    unsigned waveOff = 0, NK = 0;
#pragma unroll
    for (int ww = 0; ww < 8; ++ww) {
        unsigned wv = scanBuf[ww];
        if (ww < wave) waveOff += wv;
        NK += wv;
    }
    unsigned incl = waveOff + v;
    unsigned kpos = incl - cnt;
    for (int q = 0; q < 12; ++q) {
        int i = base + q;
        if (i < NSEL) {
            bool kp = (keepbits >> q) & 1u;
            unsigned pos = kp ? kpos : (NK + (unsigned)i - kpos);
            if (kp) kpos++;
            if (pos < NOUT) out[pos] = boxes[i];
        }
    }
}

extern "C" void kernel_launch(void* const* d_in, const int* in_sizes, int n_in,
                              void* d_out, int out_size, void* d_ws, size_t ws_size,
                              hipStream_t stream) {
    const float* scores = (const float*)d_in[0];
    const float* bbox = (const float*)d_in[1];
    const float* im_info = (const float*)d_in[2];
    char* ws = (char*)d_ws;

    unsigned* histG = (unsigned*)(ws + WS_HIST);
    unsigned* binB = (unsigned*)(ws + WS_BINB);
    unsigned* nact = (unsigned*)(ws + WS_NACT);
    unsigned* activeList = (unsigned*)(ws + WS_ACTIVE);
    unsigned* binStart = (unsigned*)(ws + WS_BINSTART);
    unsigned long long* selKeys = (unsigned long long*)(ws + WS_SELKEYS);
    float4* boxes = (float4*)(ws + WS_BOXES);
    unsigned long long* supT = (unsigned long long*)(ws + WS_MASK);
    float4* out = (float4*)d_out;

    k_front1<<<1, 1024, 0, stream>>>(scores, histG, binB, binStart, activeList, nact, selKeys);
    k_binsort<<<64, 256, 0, stream>>>(histG, binStart, activeList, nact, selKeys, bbox, im_info, boxes);
    k_mask<<<MASK_BLOCKS, 256, 0, stream>>>(boxes, supT);
    k_nms<<<1, 512, 0, stream>>>(supT, boxes, out);
}